// Round 4
// baseline (58.391 us; speedup 1.0000x reference)
//
#include <hip/hip_runtime.h>
#include <stdint.h>

// ChiSquareLoss: per-image RGB 256-bin histograms of two [B,3,512,512] f32
// tensors, normalized, chi-square over 768 bins, mean over batch.
//
// R3: LDS atomics are the measured wall (~1.2 lane-atomics/cyc/CU; R0-R2 all
// ~73us with identical atomic counts). Replace with per-thread PRIVATE byte
// histograms (no atomics): ds_read_u8 / add / ds_write_b8, per-wave in-order
// DS pipe gives write->read ordering. Same-bin hazards inside a float4 batch
// are resolved with 6 compares (increment accumulation; last in-order write
// wins). Epochs of 128 elems/thread -> byte counters can NEVER overflow.
// Region stride 260B -> bank = (tid + bin/4) & 31 (2-way, free).
// Grid 512 = exactly 2 blocks/CU @ 74752B LDS (66560 hist + 8192 stage).

#define NCH       3
#define BINS      256
#define CBINS     (NCH * BINS)          // 768
#define THREADS   256
#define EPOCHS    3
#define F4_PER_CHUNK 8192               // divides 65536 -> chunk is channel-uniform
#define F4_PER_THREAD 32                // per epoch; 128 elems -> byte-safe
#define REG_WORDS 65                    // 260 B per-thread region (1-word pad)
#define HIST_WORDS (THREADS * REG_WORDS)        // 16640 words = 66560 B
#define STAGE_WORDS (THREADS * 8)               // 2048 words  = 8192 B
#define LDS_BYTES ((HIST_WORDS + STAGE_WORDS) * 4)  // 74752 B

__global__ __launch_bounds__(THREADS)
void hist_kernel(const float* __restrict__ in0,
                 const float* __restrict__ in1,
                 unsigned int* __restrict__ ghist,   // [2][B][768]
                 int B) {
    extern __shared__ uint32_t lds[];               // [HIST | STAGE]
    uint32_t* const stage = lds + HIST_WORDS;
    unsigned char* const lb = (unsigned char*)lds;

    const int tid = threadIdx.x;
    const int bid = blockIdx.x;

    for (int e = 0; e < EPOCHS; ++e) {
        const int g     = bid * EPOCHS + e;         // global chunk id
        const int input = g / 768;                  // 768 chunks per input
        const int gi    = g - input * 768;
        const int img   = gi / 24;                  // 24 chunks per image
        const int c24   = gi - img * 24;
        const int ch    = c24 >> 3;                 // 8 chunks per channel

        const float4* __restrict__ src = (const float4*)(input ? in1 : in0)
            + (size_t)img * 196608 + (size_t)c24 * F4_PER_CHUNK;

        // prefetch batch 0 (issue before zeroing so vmcnt overlaps)
        float4 va[8], vb[8];
        #pragma unroll
        for (int j = 0; j < 8; ++j) va[j] = src[j * THREADS + tid];

        // zero hist (16640 words = 4160 uint4; 16 full rounds + 64 tail)
        uint4* z = (uint4*)lds;
        #pragma unroll
        for (int i = 0; i < 16; ++i) z[tid + i * THREADS] = make_uint4(0u,0u,0u,0u);
        if (tid < (HIST_WORDS / 4 - 16 * THREADS)) z[tid + 16 * THREADS] = make_uint4(0u,0u,0u,0u);
        __syncthreads();

        unsigned char* const h = lb + tid * (REG_WORDS * 4);   // private 256 bins

        #pragma unroll
        for (int qb = 0; qb < 4; ++qb) {
            float4* cur = (qb & 1) ? vb : va;
            float4* nxt = (qb & 1) ? va : vb;
            if (qb < 3) {
                #pragma unroll
                for (int j = 0; j < 8; ++j)
                    nxt[j] = src[((qb + 1) * 8 + j) * THREADS + tid];
            }
            #pragma unroll
            for (int j = 0; j < 8; ++j) {
                const float4 v = cur[j];
                const unsigned b0 = (unsigned)fminf(fmaxf(v.x * 255.0f, 0.0f), 255.0f);
                const unsigned b1 = (unsigned)fminf(fmaxf(v.y * 255.0f, 0.0f), 255.0f);
                const unsigned b2 = (unsigned)fminf(fmaxf(v.z * 255.0f, 0.0f), 255.0f);
                const unsigned b3 = (unsigned)fminf(fmaxf(v.w * 255.0f, 0.0f), 255.0f);
                // reads all issued before writes (may-alias: compiler preserves);
                // duplicate bins read the same stale value -> dedupe increments,
                // in-order DS writes make the last (largest) write win.
                const unsigned r0 = h[b0];
                const unsigned r1 = h[b1];
                const unsigned r2 = h[b2];
                const unsigned r3 = h[b3];
                const unsigned e1 = (b1 == b0);
                const unsigned e2 = (unsigned)(b2 == b0) + (unsigned)(b2 == b1);
                const unsigned e3 = (unsigned)(b3 == b0) + (unsigned)(b3 == b1) + (unsigned)(b3 == b2);
                h[b0] = (unsigned char)(r0 + 1u);
                h[b1] = (unsigned char)(r1 + 1u + e1);
                h[b2] = (unsigned char)(r2 + 1u + e2);
                h[b3] = (unsigned char)(r3 + 1u + e3);
            }
        }
        __syncthreads();

        // flush phase 1: packed column sums. thread t: bins [bg*16, bg*16+16)
        // over regions [rg*16, rg*16+16). u16 lanes hold sums <= 16*128 = 2048.
        {
            const int bg = tid & 15, rg = tid >> 4;
            uint32_t accE[4] = {0,0,0,0}, accO[4] = {0,0,0,0};
            #pragma unroll
            for (int k = 0; k < 16; ++k) {
                const uint32_t* w = lds + (rg * 16 + k) * REG_WORDS + bg * 4;
                #pragma unroll
                for (int j = 0; j < 4; ++j) {
                    const uint32_t x = w[j];
                    accE[j] += x & 0x00FF00FFu;
                    accO[j] += (x >> 8) & 0x00FF00FFu;
                }
            }
            #pragma unroll
            for (int j = 0; j < 4; ++j) {
                stage[tid * 8 + j * 2]     = accE[j];
                stage[tid * 8 + j * 2 + 1] = accO[j];
            }
        }
        __syncthreads();

        // flush phase 2: thread t owns bin t; sum 16 rgroup partials, one
        // global atomic per bin per block-epoch.
        {
            const int b   = tid;
            const int bg2 = b >> 4;
            const int jw  = (b & 15) >> 2;
            const int sub = b & 3;               // 0:E.lo 1:O.lo 2:E.hi 3:O.hi
            const int sel = jw * 2 + (sub & 1);
            const int sh  = (sub >> 1) * 16;
            uint32_t sum = 0;
            #pragma unroll
            for (int rg2 = 0; rg2 < 16; ++rg2)
                sum += (stage[(rg2 * 16 + bg2) * 8 + sel] >> sh) & 0xFFFFu;
            atomicAdd(&ghist[((size_t)(input * B + img) * NCH + ch) * BINS + b], sum);
        }
        // next epoch's zero-barrier orders stage reuse; no extra barrier needed
    }
}

__global__ __launch_bounds__(1024)
void chi_kernel(const unsigned int* __restrict__ ghist, float* __restrict__ out, int B) {
    const unsigned int* __restrict__ h1 = ghist;
    const unsigned int* __restrict__ h2 = ghist + (size_t)B * CBINS;
    const int total = B * CBINS;
    const float N = (float)(NCH * 512 * 512);   // 786432, exact per-image sum

    double acc = 0.0;
    for (int i = threadIdx.x; i < total; i += 1024) {
        float a1 = (float)h1[i] / N;
        float a2 = (float)h2[i] / N;
        float d = a1 - a2;
        float sm = a1 + a2 + 1e-10f;
        acc += (double)(d * d / sm);
    }

    #pragma unroll
    for (int off = 32; off > 0; off >>= 1)
        acc += __shfl_down(acc, off);

    __shared__ double wsum[16];
    if ((threadIdx.x & 63) == 0) wsum[threadIdx.x >> 6] = acc;
    __syncthreads();
    if (threadIdx.x == 0) {
        double t = 0.0;
        #pragma unroll
        for (int i = 0; i < 16; ++i) t += wsum[i];
        out[0] = (float)(t / (double)B);
    }
}

extern "C" void kernel_launch(void* const* d_in, const int* in_sizes, int n_in,
                              void* d_out, int out_size, void* d_ws, size_t ws_size,
                              hipStream_t stream) {
    const float* in0 = (const float*)d_in[0];
    const float* in1 = (const float*)d_in[1];
    const int B = in_sizes[0] / (NCH * 512 * 512);   // 32

    unsigned int* ghist = (unsigned int*)d_ws;
    const size_t hist_bytes = (size_t)2 * B * CBINS * sizeof(unsigned int);
    const int grid = 2 * B * 24 / EPOCHS;            // 512 = exactly 2 blocks/CU

    hipMemsetAsync(d_ws, 0, hist_bytes, stream);
    hist_kernel<<<grid, THREADS, LDS_BYTES, stream>>>(in0, in1, ghist, B);
    chi_kernel<<<1, 1024, 0, stream>>>(ghist, (float*)d_out, B);
}